// Round 4
// baseline (875.474 us; speedup 1.0000x reference)
//
#include <hip/hip_runtime.h>
#include <math.h>

#define NB 2
#define NH 16
#define LSEQ 2048
#define DD 64
#define HSZ (LSEQ*DD)            // 131072 elements per (b,h)
#define NELEM (NB*NH*HSZ)        // 4194304 per tensor

typedef _Float16 half_t;
typedef _Float16 f16x4 __attribute__((ext_vector_type(4)));
typedef _Float16 f16x8 __attribute__((ext_vector_type(8)));
typedef float    f32x4 __attribute__((ext_vector_type(4)));

// ---------------- K0a: q f32 -> f16 ----------------
__global__ __launch_bounds__(256) void convert_q(
    const float* __restrict__ q, half_t* __restrict__ qh)
{
    const int n4 = NELEM / 4;
    for (int gid = blockIdx.x * 256 + threadIdx.x; gid < n4; gid += gridDim.x * 256) {
        float4 x = ((const float4*)q)[gid];
        f16x4 y;
        y[0] = (half_t)x.x; y[1] = (half_t)x.y; y[2] = (half_t)x.z; y[3] = (half_t)x.w;
        ((f16x4*)qh)[gid] = y;
    }
}

// ---------------- K0b: transpose+convert K-view and V ----------------
// z=0: per (b,h) k-block viewed [64][2048] f32  -> kt [2048][64] f16
// z=1: per (b,h) v-block        [2048][64] f32  -> vt [64][2048] f16
__global__ __launch_bounds__(256) void transpose_cvt(
    const float* __restrict__ k, const float* __restrict__ v,
    half_t* __restrict__ kt, half_t* __restrict__ vt)
{
    __shared__ half_t lds[64][72];
    const int tid = threadIdx.x;
    const int bh  = blockIdx.y;
    const int t64 = blockIdx.x;      // 0..31
    const float* src; half_t* dst; int C, R, r0, c0;
    if (blockIdx.z == 0) {
        src = k + (size_t)bh * HSZ; dst = kt + (size_t)bh * HSZ;
        R = 64; C = LSEQ; r0 = 0; c0 = t64 * 64;
    } else {
        src = v + (size_t)bh * HSZ; dst = vt + (size_t)bh * HSZ;
        R = LSEQ; C = 64; r0 = t64 * 64; c0 = 0;
    }
    const int rr = tid & 63, w4 = tid >> 6;
    #pragma unroll
    for (int qq = 0; qq < 4; ++qq) {
        float4 x = *(const float4*)&src[(size_t)(r0 + rr) * C + c0 + w4 * 16 + qq * 4];
        lds[w4 * 16 + qq * 4 + 0][rr] = (half_t)x.x;
        lds[w4 * 16 + qq * 4 + 1][rr] = (half_t)x.y;
        lds[w4 * 16 + qq * 4 + 2][rr] = (half_t)x.z;
        lds[w4 * 16 + qq * 4 + 3][rr] = (half_t)x.w;
    }
    __syncthreads();
    #pragma unroll
    for (int p = 0; p < 2; ++p) {
        const int id = tid + p * 256;
        const int cl = id >> 3, rc = id & 7;
        f16x8 y = *(const f16x8*)&lds[cl][rc * 8];
        *(f16x8*)&dst[(size_t)(c0 + cl) * R + r0 + rc * 8] = y;
    }
}

// ---------------- Fused: QK^T(view) + head-softmax + score store + PV --------
// block = (b, 16 i-rows); 4 waves, wave w owns heads 4w..4w+3; loop j in 32s.
// QK swapped (A=kt rows, B=q rows) -> C holds S^T: lane(g,n): i=i0+n,
// j=j0+jb*16+4g+r  [C/D map HW-verified]. That register layout IS the
// B-fragment of mfma_f32_16x16x16f16 (4 contiguous k per lane-group), so P
// feeds PV directly; PV computes out^T (A=vt rows d, k=j).
__global__ __launch_bounds__(256, 1) void fused_attn(
    const half_t* __restrict__ qh, const half_t* __restrict__ kt,
    const half_t* __restrict__ vt, const int* __restrict__ mask,
    float* __restrict__ score, float* __restrict__ out)
{
    __shared__ float smem[4352];  // 2x 2112 red bufs; reused as 4x 1088 epilogue
    const int tid = threadIdx.x, w = tid >> 6, lane = tid & 63;
    const int n16 = lane & 15, g = lane >> 4;
    const int g4 = g * 4, g8 = g * 8;
    const int i0 = blockIdx.x * 16, b = blockIdx.y;
    const size_t hb0 = (size_t)b * NH;
    const int h0 = w * 4;
    const int irow = i0 + n16;

    // hoisted q B-frags (loop-invariant): B[k][col i]=q[i0+n][k]
    f16x8 qf[4][2];
    #pragma unroll
    for (int hh = 0; hh < 4; ++hh)
        #pragma unroll
        for (int kg = 0; kg < 2; ++kg)
            qf[hh][kg] = *(const f16x8*)(qh + (hb0 + h0 + hh) * (size_t)HSZ
                                         + (size_t)irow * DD + kg * 32 + g8);

    f32x4 acc[4][4];  // [head][d-subtile] = out^T C-tiles
    #pragma unroll
    for (int hh = 0; hh < 4; ++hh)
        #pragma unroll
        for (int ds = 0; ds < 4; ++ds) { acc[hh][ds][0]=0.f; acc[hh][ds][1]=0.f; acc[hh][ds][2]=0.f; acc[hh][ds][3]=0.f; }

    const int* mrow = mask + ((size_t)b * LSEQ + irow) * LSEQ;

    for (int t = 0; t < 64; ++t) {
        const int j0 = t * 32;
        int4 m0 = *(const int4*)(mrow + j0 + g4);
        int4 m1 = *(const int4*)(mrow + j0 + 16 + g4);
        int mvv[2][4] = {{m0.x, m0.y, m0.z, m0.w}, {m1.x, m1.y, m1.z, m1.w}};

        // ---- S^T tiles for this wave's 4 heads
        f32x4 sc[4][2];
        #pragma unroll
        for (int hh = 0; hh < 4; ++hh) {
            const half_t* kp = kt + (hb0 + h0 + hh) * (size_t)HSZ;
            #pragma unroll
            for (int jb = 0; jb < 2; ++jb) {
                const half_t* kr = kp + (size_t)(j0 + jb * 16 + n16) * DD;
                f16x8 k0 = *(const f16x8*)(kr + g8);
                f16x8 k1 = *(const f16x8*)(kr + 32 + g8);
                f32x4 c = {0.f, 0.f, 0.f, 0.f};
                c = __builtin_amdgcn_mfma_f32_16x16x32_f16(k0, qf[hh][0], c, 0, 0, 0);
                c = __builtin_amdgcn_mfma_f32_16x16x32_f16(k1, qf[hh][1], c, 0, 0, 0);
                sc[hh][jb] = c;
            }
        }

        // ---- exp (no max-subtract; masked -> e=1 for all heads => P=1/16)
        f32x4 ps[2] = {{0.f,0.f,0.f,0.f}, {0.f,0.f,0.f,0.f}};
        #pragma unroll
        for (int hh = 0; hh < 4; ++hh)
            #pragma unroll
            for (int jb = 0; jb < 2; ++jb)
                #pragma unroll
                for (int r = 0; r < 4; ++r) {
                    float e = (mvv[jb][r] == 0) ? 1.0f : __expf(0.125f * sc[hh][jb][r]);
                    sc[hh][jb][r] = e;
                    ps[jb][r] += e;
                }

        // ---- cross-wave sum (4 head-groups); stride 132 pads banks
        float* red = smem + (t & 1) * 2112;
        #pragma unroll
        for (int jb = 0; jb < 2; ++jb)
            #pragma unroll
            for (int r = 0; r < 4; ++r)
                red[n16 * 132 + (jb * 16 + g4 + r) * 4 + w] = ps[jb][r];
        asm volatile("s_waitcnt lgkmcnt(0)" ::: "memory");
        __builtin_amdgcn_s_barrier();   // lgkm-only: global loads stay in flight

        float inv_[2][4];
        #pragma unroll
        for (int jb = 0; jb < 2; ++jb)
            #pragma unroll
            for (int r = 0; r < 4; ++r) {
                f32x4 s4 = *(const f32x4*)&red[n16 * 132 + (jb * 16 + g4 + r) * 4];
                inv_[jb][r] = 1.0f / (s4[0] + s4[1] + s4[2] + s4[3]);
            }

        // ---- P: store to score (float4) + PV accumulate straight from regs
        #pragma unroll
        for (int hh = 0; hh < 4; ++hh) {
            float* srow = score + ((hb0 + h0 + hh) * LSEQ + irow) * LSEQ + j0;
            const half_t* vp = vt + (hb0 + h0 + hh) * (size_t)HSZ;
            #pragma unroll
            for (int jb = 0; jb < 2; ++jb) {
                f32x4 p; f16x4 pb;
                #pragma unroll
                for (int r = 0; r < 4; ++r) { p[r] = sc[hh][jb][r] * inv_[jb][r]; pb[r] = (half_t)p[r]; }
                *(f32x4*)(srow + jb * 16 + g4) = p;
                #pragma unroll
                for (int ds = 0; ds < 4; ++ds) {
                    f16x4 av = *(const f16x4*)(vp + (size_t)(ds * 16 + n16) * LSEQ + j0 + jb * 16 + g4);
                    acc[hh][ds] = __builtin_amdgcn_mfma_f32_16x16x16f16(av, pb, acc[hh][ds], 0, 0, 0);
                }
            }
        }
    }

    // ---- epilogue: wave-local LDS transpose of out^T -> coalesced float4
    __syncthreads();
    float* ep = smem + w * 1088;   // 16 rows x stride 68
    const int il = lane >> 2, cc = lane & 3;
    #pragma unroll
    for (int hh = 0; hh < 4; ++hh) {
        #pragma unroll
        for (int ds = 0; ds < 4; ++ds)
            #pragma unroll
            for (int r = 0; r < 4; ++r)
                ep[n16 * 68 + ds * 16 + g4 + r] = acc[hh][ds][r];
        asm volatile("s_waitcnt lgkmcnt(0)" ::: "memory");
        float* orow = out + (hb0 + h0 + hh) * (size_t)HSZ + (size_t)(i0 + il) * DD + cc * 16;
        #pragma unroll
        for (int qq = 0; qq < 4; ++qq) {
            f32x4 x = *(const f32x4*)&ep[il * 68 + cc * 16 + qq * 4];
            *(f32x4*)(orow + qq * 4) = x;
        }
        asm volatile("s_waitcnt lgkmcnt(0)" ::: "memory");
    }
}

extern "C" void kernel_launch(void* const* d_in, const int* in_sizes, int n_in,
                              void* d_out, int out_size, void* d_ws, size_t ws_size,
                              hipStream_t stream) {
    const float* q    = (const float*)d_in[0];
    const float* k    = (const float*)d_in[1];
    const float* v    = (const float*)d_in[2];
    const int*   mask = (const int*)d_in[3];

    float* out   = (float*)d_out;
    float* score = out + (size_t)NB * NH * LSEQ * DD;

    half_t* qh = (half_t*)d_ws;          // 8 MB
    half_t* kt = qh + NELEM;             // 8 MB  kt[b,h][j][d]
    half_t* vt = kt + NELEM;             // 8 MB  vt[b,h][d][j]

    convert_q<<<2048, 256, 0, stream>>>(q, qh);
    transpose_cvt<<<dim3(32, NB * NH, 2), 256, 0, stream>>>(k, v, kt, vt);
    fused_attn<<<dim3(LSEQ / 16, NB), 256, 0, stream>>>(qh, kt, vt, mask, score, out);
}

// Round 5
// 759.031 us; speedup vs baseline: 1.1534x; 1.1534x over previous
//
#include <hip/hip_runtime.h>
#include <math.h>

#define NB 2
#define NH 16
#define LSEQ 2048
#define DD 64
#define HSZ (LSEQ*DD)            // 131072 elements per (b,h)
#define NELEM (NB*NH*HSZ)        // 4194304 per tensor
#define NSLICE 4

typedef _Float16 half_t;
typedef _Float16 f16x4 __attribute__((ext_vector_type(4)));
typedef _Float16 f16x8 __attribute__((ext_vector_type(8)));
typedef float    f32x4 __attribute__((ext_vector_type(4)));

// ---------------- K0a: q f32 -> f16 ----------------
__global__ __launch_bounds__(256) void convert_q(
    const float* __restrict__ q, half_t* __restrict__ qh)
{
    const int n4 = NELEM / 4;
    for (int gid = blockIdx.x * 256 + threadIdx.x; gid < n4; gid += gridDim.x * 256) {
        float4 x = ((const float4*)q)[gid];
        f16x4 y;
        y[0] = (half_t)x.x; y[1] = (half_t)x.y; y[2] = (half_t)x.z; y[3] = (half_t)x.w;
        ((f16x4*)qh)[gid] = y;
    }
}

// ---------------- K0b: transpose+convert K-view and V ----------------
__global__ __launch_bounds__(256) void transpose_cvt(
    const float* __restrict__ k, const float* __restrict__ v,
    half_t* __restrict__ kt, half_t* __restrict__ vt)
{
    __shared__ half_t lds[64][72];
    const int tid = threadIdx.x;
    const int bh  = blockIdx.y;
    const int t64 = blockIdx.x;      // 0..31
    const float* src; half_t* dst; int C, R, r0, c0;
    if (blockIdx.z == 0) {
        src = k + (size_t)bh * HSZ; dst = kt + (size_t)bh * HSZ;
        R = 64; C = LSEQ; r0 = 0; c0 = t64 * 64;
    } else {
        src = v + (size_t)bh * HSZ; dst = vt + (size_t)bh * HSZ;
        R = LSEQ; C = 64; r0 = t64 * 64; c0 = 0;
    }
    const int rr = tid & 63, w4 = tid >> 6;
    #pragma unroll
    for (int qq = 0; qq < 4; ++qq) {
        float4 x = *(const float4*)&src[(size_t)(r0 + rr) * C + c0 + w4 * 16 + qq * 4];
        lds[w4 * 16 + qq * 4 + 0][rr] = (half_t)x.x;
        lds[w4 * 16 + qq * 4 + 1][rr] = (half_t)x.y;
        lds[w4 * 16 + qq * 4 + 2][rr] = (half_t)x.z;
        lds[w4 * 16 + qq * 4 + 3][rr] = (half_t)x.w;
    }
    __syncthreads();
    #pragma unroll
    for (int p = 0; p < 2; ++p) {
        const int id = tid + p * 256;
        const int cl = id >> 3, rc = id & 7;
        f16x8 y = *(const f16x8*)&lds[cl][rc * 8];
        *(f16x8*)&dst[(size_t)(c0 + cl) * R + r0 + rc * 8] = y;
    }
}

// ------ Fused (j-sliced): QK^T + head-softmax + score store + partial PV -----
// grid (i-tile 128, jslice 4, b 2) = 1024 blocks; 4 waves, wave w = heads 4w..4w+3.
// Each block sweeps 16 j-steps (512 j) and writes partial out to pout[slice].
// Reduce LDS layout: word=(jcol*4+w)*17+n16 -> bank=(16g+n16+c)%32 = 2-way (free).
__global__ __launch_bounds__(256, 4) void fused_attn_part(
    const half_t* __restrict__ qh, const half_t* __restrict__ kt,
    const half_t* __restrict__ vt, const int* __restrict__ mask,
    float* __restrict__ score, float* __restrict__ pout)
{
    __shared__ float smem[4352];  // 2x2176 reduce bufs; reused as 4x1088 epilogue
    const int tid = threadIdx.x, w = tid >> 6, lane = tid & 63;
    const int n16 = lane & 15, g = lane >> 4;
    const int g4 = g * 4, g8 = g * 8;
    const int i0 = blockIdx.x * 16;
    const int t0 = blockIdx.y * 16;           // j-slice: steps t0..t0+15
    const int b  = blockIdx.z;
    const size_t hb0 = (size_t)b * NH;
    const int h0 = w * 4;
    const int irow = i0 + n16;

    // hoisted q B-frags (loop-invariant)
    f16x8 qf[4][2];
    #pragma unroll
    for (int hh = 0; hh < 4; ++hh)
        #pragma unroll
        for (int kg = 0; kg < 2; ++kg)
            qf[hh][kg] = *(const f16x8*)(qh + (hb0 + h0 + hh) * (size_t)HSZ
                                         + (size_t)irow * DD + kg * 32 + g8);

    f32x4 acc[4][4];  // [head][d-subtile] partial out^T
    #pragma unroll
    for (int hh = 0; hh < 4; ++hh)
        #pragma unroll
        for (int ds = 0; ds < 4; ++ds) { acc[hh][ds][0]=0.f; acc[hh][ds][1]=0.f; acc[hh][ds][2]=0.f; acc[hh][ds][3]=0.f; }

    const int* mrow = mask + ((size_t)b * LSEQ + irow) * LSEQ;

    for (int t = t0; t < t0 + 16; ++t) {
        const int j0 = t * 32;
        int4 m0 = *(const int4*)(mrow + j0 + g4);
        int4 m1 = *(const int4*)(mrow + j0 + 16 + g4);
        int mvv[2][4] = {{m0.x, m0.y, m0.z, m0.w}, {m1.x, m1.y, m1.z, m1.w}};

        // ---- S^T tiles for this wave's 4 heads
        f32x4 sc[4][2];
        #pragma unroll
        for (int hh = 0; hh < 4; ++hh) {
            const half_t* kp = kt + (hb0 + h0 + hh) * (size_t)HSZ;
            #pragma unroll
            for (int jb = 0; jb < 2; ++jb) {
                const half_t* kr = kp + (size_t)(j0 + jb * 16 + n16) * DD;
                f16x8 k0 = *(const f16x8*)(kr + g8);
                f16x8 k1 = *(const f16x8*)(kr + 32 + g8);
                f32x4 c = {0.f, 0.f, 0.f, 0.f};
                c = __builtin_amdgcn_mfma_f32_16x16x32_f16(k0, qf[hh][0], c, 0, 0, 0);
                c = __builtin_amdgcn_mfma_f32_16x16x32_f16(k1, qf[hh][1], c, 0, 0, 0);
                sc[hh][jb] = c;
            }
        }

        // ---- exp (no max-subtract; masked -> e=1 for all heads => P=1/16)
        f32x4 ps[2] = {{0.f,0.f,0.f,0.f}, {0.f,0.f,0.f,0.f}};
        #pragma unroll
        for (int hh = 0; hh < 4; ++hh)
            #pragma unroll
            for (int jb = 0; jb < 2; ++jb)
                #pragma unroll
                for (int r = 0; r < 4; ++r) {
                    float e = (mvv[jb][r] == 0) ? 1.0f : __expf(0.125f * sc[hh][jb][r]);
                    sc[hh][jb][r] = e;
                    ps[jb][r] += e;
                }

        // ---- cross-wave sum; layout word=(jcol*4+w)*17+n16 (2-way banks)
        float* red = smem + (t & 1) * 2176;
        #pragma unroll
        for (int jb = 0; jb < 2; ++jb)
            #pragma unroll
            for (int r = 0; r < 4; ++r)
                red[((jb * 16 + g4 + r) * 4 + w) * 17 + n16] = ps[jb][r];
        asm volatile("s_waitcnt lgkmcnt(0)" ::: "memory");
        __builtin_amdgcn_s_barrier();   // lgkm-only: global loads stay in flight

        float inv_[2][4];
        #pragma unroll
        for (int jb = 0; jb < 2; ++jb)
            #pragma unroll
            for (int r = 0; r < 4; ++r) {
                const int jc = (jb * 16 + g4 + r) * 4;
                float s = red[(jc + 0) * 17 + n16] + red[(jc + 1) * 17 + n16]
                        + red[(jc + 2) * 17 + n16] + red[(jc + 3) * 17 + n16];
                inv_[jb][r] = 1.0f / s;
            }

        // ---- P: store score (float4) + PV accumulate from regs
        #pragma unroll
        for (int hh = 0; hh < 4; ++hh) {
            float* srow = score + ((hb0 + h0 + hh) * LSEQ + irow) * LSEQ + j0;
            const half_t* vp = vt + (hb0 + h0 + hh) * (size_t)HSZ;
            #pragma unroll
            for (int jb = 0; jb < 2; ++jb) {
                f32x4 p; f16x4 pb;
                #pragma unroll
                for (int r = 0; r < 4; ++r) { p[r] = sc[hh][jb][r] * inv_[jb][r]; pb[r] = (half_t)p[r]; }
                *(f32x4*)(srow + jb * 16 + g4) = p;
                #pragma unroll
                for (int ds = 0; ds < 4; ++ds) {
                    f16x4 av = *(const f16x4*)(vp + (size_t)(ds * 16 + n16) * LSEQ + j0 + jb * 16 + g4);
                    acc[hh][ds] = __builtin_amdgcn_mfma_f32_16x16x16f16(av, pb, acc[hh][ds], 0, 0, 0);
                }
            }
        }
    }

    // ---- epilogue: wave-local LDS transpose of partial out^T -> coalesced
    __syncthreads();
    float* pbase = pout + (size_t)blockIdx.y * NELEM;
    float* ep = smem + w * 1088;   // 16 rows x stride 68
    const int il = lane >> 2, cc = lane & 3;
    #pragma unroll
    for (int hh = 0; hh < 4; ++hh) {
        #pragma unroll
        for (int ds = 0; ds < 4; ++ds)
            #pragma unroll
            for (int r = 0; r < 4; ++r)
                ep[n16 * 68 + ds * 16 + g4 + r] = acc[hh][ds][r];
        asm volatile("s_waitcnt lgkmcnt(0)" ::: "memory");
        float* orow = pbase + (hb0 + h0 + hh) * (size_t)HSZ + (size_t)(i0 + il) * DD + cc * 16;
        #pragma unroll
        for (int qq = 0; qq < 4; ++qq) {
            f32x4 x = *(const f32x4*)&ep[il * 68 + cc * 16 + qq * 4];
            *(f32x4*)(orow + qq * 4) = x;
        }
        asm volatile("s_waitcnt lgkmcnt(0)" ::: "memory");
    }
}

// ---------------- Reduce: out = sum of 4 partial slices ----------------
__global__ __launch_bounds__(256) void reduce_out(
    const float* __restrict__ pout, float* __restrict__ out)
{
    const int n4 = NELEM / 4;
    for (int i = blockIdx.x * 256 + threadIdx.x; i < n4; i += gridDim.x * 256) {
        f32x4 a = ((const f32x4*)pout)[i];
        f32x4 bb = ((const f32x4*)(pout + NELEM))[i];
        f32x4 c = ((const f32x4*)(pout + 2 * (size_t)NELEM))[i];
        f32x4 d = ((const f32x4*)(pout + 3 * (size_t)NELEM))[i];
        ((f32x4*)out)[i] = a + bb + c + d;
    }
}

extern "C" void kernel_launch(void* const* d_in, const int* in_sizes, int n_in,
                              void* d_out, int out_size, void* d_ws, size_t ws_size,
                              hipStream_t stream) {
    const float* q    = (const float*)d_in[0];
    const float* k    = (const float*)d_in[1];
    const float* v    = (const float*)d_in[2];
    const int*   mask = (const int*)d_in[3];

    float* out   = (float*)d_out;
    float* score = out + (size_t)NB * NH * LSEQ * DD;

    half_t* qh   = (half_t*)d_ws;            // 8 MB
    half_t* kt   = qh + NELEM;               // 8 MB  kt[b,h][j][d]
    half_t* vt   = kt + NELEM;               // 8 MB  vt[b,h][d][j]
    float*  pout = (float*)(vt + NELEM);     // 4 x 16 MB partial outputs

    convert_q<<<2048, 256, 0, stream>>>(q, qh);
    transpose_cvt<<<dim3(32, NB * NH, 2), 256, 0, stream>>>(k, v, kt, vt);
    fused_attn_part<<<dim3(LSEQ / 16, NSLICE, NB), 256, 0, stream>>>(qh, kt, vt, mask, score, pout);
    reduce_out<<<1024, 256, 0, stream>>>(pout, out);
}

// Round 6
// 613.238 us; speedup vs baseline: 1.4276x; 1.2377x over previous
//
#include <hip/hip_runtime.h>
#include <math.h>

#define NB 2
#define NH 16
#define LSEQ 2048
#define DD 64
#define HSZ (LSEQ*DD)            // 131072 elements per (b,h)
#define NELEM (NB*NH*HSZ)        // 4194304 per tensor
#define NSLICE 4

typedef _Float16 half_t;
typedef _Float16 f16x4 __attribute__((ext_vector_type(4)));
typedef _Float16 f16x8 __attribute__((ext_vector_type(8)));
typedef float    f32x4 __attribute__((ext_vector_type(4)));
typedef int      i32x4 __attribute__((ext_vector_type(4)));

// ---------------- K0a: q f32 -> f16 (nt loads: q never re-read) -------------
__global__ __launch_bounds__(256) void convert_q(
    const float* __restrict__ q, half_t* __restrict__ qh)
{
    const int n4 = NELEM / 4;
    for (int gid = blockIdx.x * 256 + threadIdx.x; gid < n4; gid += gridDim.x * 256) {
        f32x4 x = __builtin_nontemporal_load((const f32x4*)q + gid);
        f16x4 y;
        y[0] = (half_t)x[0]; y[1] = (half_t)x[1]; y[2] = (half_t)x[2]; y[3] = (half_t)x[3];
        ((f16x4*)qh)[gid] = y;
    }
}

// ---------------- K0b: transpose+convert K-view and V ----------------
__global__ __launch_bounds__(256) void transpose_cvt(
    const float* __restrict__ k, const float* __restrict__ v,
    half_t* __restrict__ kt, half_t* __restrict__ vt)
{
    __shared__ half_t lds[64][72];
    const int tid = threadIdx.x;
    const int bh  = blockIdx.y;
    const int t64 = blockIdx.x;      // 0..31
    const float* src; half_t* dst; int C, R, r0, c0;
    if (blockIdx.z == 0) {
        src = k + (size_t)bh * HSZ; dst = kt + (size_t)bh * HSZ;
        R = 64; C = LSEQ; r0 = 0; c0 = t64 * 64;
    } else {
        src = v + (size_t)bh * HSZ; dst = vt + (size_t)bh * HSZ;
        R = LSEQ; C = 64; r0 = t64 * 64; c0 = 0;
    }
    const int rr = tid & 63, w4 = tid >> 6;
    #pragma unroll
    for (int qq = 0; qq < 4; ++qq) {
        f32x4 x = __builtin_nontemporal_load(
            (const f32x4*)&src[(size_t)(r0 + rr) * C + c0 + w4 * 16 + qq * 4]);
        lds[w4 * 16 + qq * 4 + 0][rr] = (half_t)x[0];
        lds[w4 * 16 + qq * 4 + 1][rr] = (half_t)x[1];
        lds[w4 * 16 + qq * 4 + 2][rr] = (half_t)x[2];
        lds[w4 * 16 + qq * 4 + 3][rr] = (half_t)x[3];
    }
    __syncthreads();
    #pragma unroll
    for (int p = 0; p < 2; ++p) {
        const int id = tid + p * 256;
        const int cl = id >> 3, rc = id & 7;
        f16x8 y = *(const f16x8*)&lds[cl][rc * 8];
        *(f16x8*)&dst[(size_t)(c0 + cl) * R + r0 + rc * 8] = y;
    }
}

// ------ Fused (j-sliced): QK^T + head-softmax + score store + partial PV -----
// grid (i-tile 128, jslice 4, b 2) = 1024 blocks; 4 waves, wave w = heads 4w..4w+3.
// Score path: P -> per-wave LDS f16 buffer -> full-128B-line nontemporal f32
// stores (8 lanes x 16B contiguous per row). Streaming outputs are nt so
// kt/vt/qh stay L2/L3-resident.
__global__ __launch_bounds__(256, 4) void fused_attn_part(
    const half_t* __restrict__ qh, const half_t* __restrict__ kt,
    const half_t* __restrict__ vt, const int* __restrict__ mask,
    float* __restrict__ score, float* __restrict__ pout)
{
    __shared__ char smem_raw[35840];
    float*  red  = (float*)smem_raw;                 // [2][2176] f32 = 17408 B
    half_t* pbuf = (half_t*)(smem_raw + 17408);      // [16 head-slot][16 i][36] f16 = 18432 B
    const int tid = threadIdx.x, w = tid >> 6, lane = tid & 63;
    const int n16 = lane & 15, g = lane >> 4;
    const int g4 = g * 4, g8 = g * 8;
    const int i0 = blockIdx.x * 16;
    const int t0 = blockIdx.y * 16;           // j-slice: steps t0..t0+15
    const int b  = blockIdx.z;
    const size_t hb0 = (size_t)b * NH;
    const int h0 = w * 4;
    const int irow = i0 + n16;

    // hoisted q B-frags (loop-invariant)
    f16x8 qf[4][2];
    #pragma unroll
    for (int hh = 0; hh < 4; ++hh)
        #pragma unroll
        for (int kg = 0; kg < 2; ++kg)
            qf[hh][kg] = *(const f16x8*)(qh + (hb0 + h0 + hh) * (size_t)HSZ
                                         + (size_t)irow * DD + kg * 32 + g8);

    f32x4 acc[4][4];  // [head][d-subtile] partial out^T
    #pragma unroll
    for (int hh = 0; hh < 4; ++hh)
        #pragma unroll
        for (int ds = 0; ds < 4; ++ds) { acc[hh][ds][0]=0.f; acc[hh][ds][1]=0.f; acc[hh][ds][2]=0.f; acc[hh][ds][3]=0.f; }

    const int* mrow = mask + ((size_t)b * LSEQ + irow) * LSEQ;

    for (int t = t0; t < t0 + 16; ++t) {
        const int j0 = t * 32;
        i32x4 m0 = __builtin_nontemporal_load((const i32x4*)(mrow + j0 + g4));
        i32x4 m1 = __builtin_nontemporal_load((const i32x4*)(mrow + j0 + 16 + g4));
        int mvv[2][4] = {{m0[0], m0[1], m0[2], m0[3]}, {m1[0], m1[1], m1[2], m1[3]}};

        // ---- S^T tiles for this wave's 4 heads
        f32x4 sc[4][2];
        #pragma unroll
        for (int hh = 0; hh < 4; ++hh) {
            const half_t* kp = kt + (hb0 + h0 + hh) * (size_t)HSZ;
            #pragma unroll
            for (int jb = 0; jb < 2; ++jb) {
                const half_t* kr = kp + (size_t)(j0 + jb * 16 + n16) * DD;
                f16x8 k0 = *(const f16x8*)(kr + g8);
                f16x8 k1 = *(const f16x8*)(kr + 32 + g8);
                f32x4 c = {0.f, 0.f, 0.f, 0.f};
                c = __builtin_amdgcn_mfma_f32_16x16x32_f16(k0, qf[hh][0], c, 0, 0, 0);
                c = __builtin_amdgcn_mfma_f32_16x16x32_f16(k1, qf[hh][1], c, 0, 0, 0);
                sc[hh][jb] = c;
            }
        }

        // ---- exp (no max-subtract; masked -> e=1 for all heads => P=1/16)
        f32x4 ps[2] = {{0.f,0.f,0.f,0.f}, {0.f,0.f,0.f,0.f}};
        #pragma unroll
        for (int hh = 0; hh < 4; ++hh)
            #pragma unroll
            for (int jb = 0; jb < 2; ++jb)
                #pragma unroll
                for (int r = 0; r < 4; ++r) {
                    float e = (mvv[jb][r] == 0) ? 1.0f : __expf(0.125f * sc[hh][jb][r]);
                    sc[hh][jb][r] = e;
                    ps[jb][r] += e;
                }

        // ---- cross-wave sum; layout word=(jcol*4+w)*17+n16 (2-way banks)
        float* rb = red + (t & 1) * 2176;
        #pragma unroll
        for (int jb = 0; jb < 2; ++jb)
            #pragma unroll
            for (int r = 0; r < 4; ++r)
                rb[((jb * 16 + g4 + r) * 4 + w) * 17 + n16] = ps[jb][r];
        asm volatile("s_waitcnt lgkmcnt(0)" ::: "memory");
        __builtin_amdgcn_s_barrier();   // lgkm-only: global loads stay in flight

        float inv_[2][4];
        #pragma unroll
        for (int jb = 0; jb < 2; ++jb)
            #pragma unroll
            for (int r = 0; r < 4; ++r) {
                const int jc = (jb * 16 + g4 + r) * 4;
                float s = rb[(jc + 0) * 17 + n16] + rb[(jc + 1) * 17 + n16]
                        + rb[(jc + 2) * 17 + n16] + rb[(jc + 3) * 17 + n16];
                inv_[jb][r] = 1.0f / s;
            }

        // ---- P: stash f16 in per-wave LDS + PV accumulate from regs
        #pragma unroll
        for (int hh = 0; hh < 4; ++hh) {
            half_t* pb_head = pbuf + (size_t)(w * 4 + hh) * 16 * 36;
            const half_t* vp = vt + (hb0 + h0 + hh) * (size_t)HSZ;
            #pragma unroll
            for (int jb = 0; jb < 2; ++jb) {
                f16x4 pb;
                #pragma unroll
                for (int r = 0; r < 4; ++r) pb[r] = (half_t)(sc[hh][jb][r] * inv_[jb][r]);
                *(f16x4*)(pb_head + n16 * 36 + jb * 16 + g4) = pb;  // 8B-aligned (stride 72B)
                #pragma unroll
                for (int ds = 0; ds < 4; ++ds) {
                    f16x4 av = *(const f16x4*)(vp + (size_t)(ds * 16 + n16) * LSEQ + j0 + jb * 16 + g4);
                    acc[hh][ds] = __builtin_amdgcn_mfma_f32_16x16x16f16(av, pb, acc[hh][ds], 0, 0, 0);
                }
            }
        }

        // ---- score store: full-128B-line nontemporal (wave-private pbuf)
        const int srow_ = lane >> 3, scol = (lane & 7) * 4;
        #pragma unroll
        for (int hh = 0; hh < 4; ++hh) {
            const half_t* pb_head = pbuf + (size_t)(w * 4 + hh) * 16 * 36;
            float* sbase = score + ((hb0 + h0 + hh) * LSEQ + i0) * LSEQ + j0;
            #pragma unroll
            for (int half_i = 0; half_i < 2; ++half_i) {
                const int row = half_i * 8 + srow_;
                f16x4 x = *(const f16x4*)(pb_head + row * 36 + scol);
                f32x4 y;
                y[0] = (float)x[0]; y[1] = (float)x[1]; y[2] = (float)x[2]; y[3] = (float)x[3];
                __builtin_nontemporal_store(y, (f32x4*)(sbase + (size_t)row * LSEQ + scol));
            }
        }
    }

    // ---- epilogue: wave-local LDS transpose of partial out^T -> full-line nt
    __syncthreads();                      // red region reused below
    float* pbase = pout + (size_t)blockIdx.y * NELEM;
    float* ep = (float*)smem_raw + w * 1088;   // 16 rows x stride 68 f32
    const int erow = lane >> 4, ecol = (lane & 15) * 4;
    #pragma unroll
    for (int hh = 0; hh < 4; ++hh) {
        #pragma unroll
        for (int ds = 0; ds < 4; ++ds)
            *(f32x4*)&ep[n16 * 68 + ds * 16 + g4] = acc[hh][ds];
        asm volatile("s_waitcnt lgkmcnt(0)" ::: "memory");
        float* obase = pbase + (hb0 + h0 + hh) * (size_t)HSZ + (size_t)i0 * DD;
        #pragma unroll
        for (int qq = 0; qq < 4; ++qq) {
            const int row = qq * 4 + erow;
            f32x4 x = *(const f32x4*)&ep[row * 68 + ecol];
            __builtin_nontemporal_store(x, (f32x4*)(obase + (size_t)row * DD + ecol));
        }
        asm volatile("s_waitcnt lgkmcnt(0)" ::: "memory");
    }
}

// ---------------- Reduce: out = sum of 4 partial slices ----------------
__global__ __launch_bounds__(256) void reduce_out(
    const float* __restrict__ pout, float* __restrict__ out)
{
    const int n4 = NELEM / 4;
    for (int i = blockIdx.x * 256 + threadIdx.x; i < n4; i += gridDim.x * 256) {
        f32x4 a = __builtin_nontemporal_load((const f32x4*)pout + i);
        f32x4 bb = __builtin_nontemporal_load((const f32x4*)(pout + NELEM) + i);
        f32x4 c = __builtin_nontemporal_load((const f32x4*)(pout + 2 * (size_t)NELEM) + i);
        f32x4 d = __builtin_nontemporal_load((const f32x4*)(pout + 3 * (size_t)NELEM) + i);
        __builtin_nontemporal_store(a + bb + c + d, (f32x4*)out + i);
    }
}

extern "C" void kernel_launch(void* const* d_in, const int* in_sizes, int n_in,
                              void* d_out, int out_size, void* d_ws, size_t ws_size,
                              hipStream_t stream) {
    const float* q    = (const float*)d_in[0];
    const float* k    = (const float*)d_in[1];
    const float* v    = (const float*)d_in[2];
    const int*   mask = (const int*)d_in[3];

    float* out   = (float*)d_out;
    float* score = out + (size_t)NB * NH * LSEQ * DD;

    half_t* qh   = (half_t*)d_ws;            // 8 MB
    half_t* kt   = qh + NELEM;               // 8 MB  kt[b,h][j][d]
    half_t* vt   = kt + NELEM;               // 8 MB  vt[b,h][d][j]
    float*  pout = (float*)(vt + NELEM);     // 4 x 16 MB partial outputs

    convert_q<<<2048, 256, 0, stream>>>(q, qh);
    transpose_cvt<<<dim3(32, NB * NH, 2), 256, 0, stream>>>(k, v, kt, vt);
    fused_attn_part<<<dim3(LSEQ / 16, NSLICE, NB), 256, 0, stream>>>(qh, kt, vt, mask, score, pout);
    reduce_out<<<1024, 256, 0, stream>>>(pout, out);
}

// Round 7
// 570.487 us; speedup vs baseline: 1.5346x; 1.0749x over previous
//
#include <hip/hip_runtime.h>
#include <math.h>

#define NB 2
#define NH 16
#define LSEQ 2048
#define DD 64
#define HSZ (LSEQ*DD)            // 131072 elements per (b,h)
#define NELEM (NB*NH*HSZ)        // 4194304 per tensor
#define NSLICE 4

typedef _Float16 half_t;
typedef _Float16 f16x4 __attribute__((ext_vector_type(4)));
typedef _Float16 f16x8 __attribute__((ext_vector_type(8)));
typedef float    f32x4 __attribute__((ext_vector_type(4)));
typedef int      i32x4 __attribute__((ext_vector_type(4)));

// ---------------- K0a: q f32 -> f16 (nt loads: q never re-read) -------------
__global__ __launch_bounds__(256) void convert_q(
    const float* __restrict__ q, half_t* __restrict__ qh)
{
    const int n4 = NELEM / 4;
    for (int gid = blockIdx.x * 256 + threadIdx.x; gid < n4; gid += gridDim.x * 256) {
        f32x4 x = __builtin_nontemporal_load((const f32x4*)q + gid);
        f16x4 y;
        y[0] = (half_t)x[0]; y[1] = (half_t)x[1]; y[2] = (half_t)x[2]; y[3] = (half_t)x[3];
        ((f16x4*)qh)[gid] = y;
    }
}

// ---------------- K0b: transpose+convert K-view and V ----------------
__global__ __launch_bounds__(256) void transpose_cvt(
    const float* __restrict__ k, const float* __restrict__ v,
    half_t* __restrict__ kt, half_t* __restrict__ vt)
{
    __shared__ half_t lds[64][72];
    const int tid = threadIdx.x;
    const int bh  = blockIdx.y;
    const int t64 = blockIdx.x;      // 0..31
    const float* src; half_t* dst; int C, R, r0, c0;
    if (blockIdx.z == 0) {
        src = k + (size_t)bh * HSZ; dst = kt + (size_t)bh * HSZ;
        R = 64; C = LSEQ; r0 = 0; c0 = t64 * 64;
    } else {
        src = v + (size_t)bh * HSZ; dst = vt + (size_t)bh * HSZ;
        R = LSEQ; C = 64; r0 = t64 * 64; c0 = 0;
    }
    const int rr = tid & 63, w4 = tid >> 6;
    #pragma unroll
    for (int qq = 0; qq < 4; ++qq) {
        f32x4 x = __builtin_nontemporal_load(
            (const f32x4*)&src[(size_t)(r0 + rr) * C + c0 + w4 * 16 + qq * 4]);
        lds[w4 * 16 + qq * 4 + 0][rr] = (half_t)x[0];
        lds[w4 * 16 + qq * 4 + 1][rr] = (half_t)x[1];
        lds[w4 * 16 + qq * 4 + 2][rr] = (half_t)x[2];
        lds[w4 * 16 + qq * 4 + 3][rr] = (half_t)x[3];
    }
    __syncthreads();
    #pragma unroll
    for (int p = 0; p < 2; ++p) {
        const int id = tid + p * 256;
        const int cl = id >> 3, rc = id & 7;
        f16x8 y = *(const f16x8*)&lds[cl][rc * 8];
        *(f16x8*)&dst[(size_t)(c0 + cl) * R + r0 + rc * 8] = y;
    }
}

// ------ Fused (j-sliced): QK^T + head-softmax + score store + partial PV -----
// 1D grid, 1024 blocks; XCD-aware decode: xcd = bid&7 owns ONE (b,jslice)
// group, so each XCD's 128 resident blocks share a single 2 MiB kt+vt slice
// (fits 4 MiB per-XCD L2). i_tile = bid>>3.
__global__ __launch_bounds__(256, 4) void fused_attn_part(
    const half_t* __restrict__ qh, const half_t* __restrict__ kt,
    const half_t* __restrict__ vt, const int* __restrict__ mask,
    float* __restrict__ score, float* __restrict__ pout)
{
    __shared__ char smem_raw[35840];
    float*  red  = (float*)smem_raw;                 // [2][2176] f32 = 17408 B
    half_t* pbuf = (half_t*)(smem_raw + 17408);      // [16 head-slot][16 i][36] f16 = 18432 B
    const int tid = threadIdx.x, w = tid >> 6, lane = tid & 63;
    const int n16 = lane & 15, g = lane >> 4;
    const int g4 = g * 4, g8 = g * 8;

    const int bid = blockIdx.x;
    const int xcd = bid & 7;                  // one group per XCD
    const int b      = xcd >> 2;
    const int jslice = xcd & 3;
    const int i0 = (bid >> 3) * 16;
    const int t0 = jslice * 16;               // j-slice: steps t0..t0+15

    const size_t hb0 = (size_t)b * NH;
    const int h0 = w * 4;
    const int irow = i0 + n16;

    // hoisted q B-frags (loop-invariant)
    f16x8 qf[4][2];
    #pragma unroll
    for (int hh = 0; hh < 4; ++hh)
        #pragma unroll
        for (int kg = 0; kg < 2; ++kg)
            qf[hh][kg] = *(const f16x8*)(qh + (hb0 + h0 + hh) * (size_t)HSZ
                                         + (size_t)irow * DD + kg * 32 + g8);

    f32x4 acc[4][4];  // [head][d-subtile] partial out^T
    #pragma unroll
    for (int hh = 0; hh < 4; ++hh)
        #pragma unroll
        for (int ds = 0; ds < 4; ++ds) { acc[hh][ds][0]=0.f; acc[hh][ds][1]=0.f; acc[hh][ds][2]=0.f; acc[hh][ds][3]=0.f; }

    const int* mrow = mask + ((size_t)b * LSEQ + irow) * LSEQ;

    for (int t = t0; t < t0 + 16; ++t) {
        const int j0 = t * 32;
        i32x4 m0 = __builtin_nontemporal_load((const i32x4*)(mrow + j0 + g4));
        i32x4 m1 = __builtin_nontemporal_load((const i32x4*)(mrow + j0 + 16 + g4));
        int mvv[2][4] = {{m0[0], m0[1], m0[2], m0[3]}, {m1[0], m1[1], m1[2], m1[3]}};

        // ---- S^T tiles for this wave's 4 heads
        f32x4 sc[4][2];
        #pragma unroll
        for (int hh = 0; hh < 4; ++hh) {
            const half_t* kp = kt + (hb0 + h0 + hh) * (size_t)HSZ;
            #pragma unroll
            for (int jb = 0; jb < 2; ++jb) {
                const half_t* kr = kp + (size_t)(j0 + jb * 16 + n16) * DD;
                f16x8 k0 = *(const f16x8*)(kr + g8);
                f16x8 k1 = *(const f16x8*)(kr + 32 + g8);
                f32x4 c = {0.f, 0.f, 0.f, 0.f};
                c = __builtin_amdgcn_mfma_f32_16x16x32_f16(k0, qf[hh][0], c, 0, 0, 0);
                c = __builtin_amdgcn_mfma_f32_16x16x32_f16(k1, qf[hh][1], c, 0, 0, 0);
                sc[hh][jb] = c;
            }
        }

        // ---- exp (no max-subtract; masked -> e=1 for all heads => P=1/16)
        f32x4 ps[2] = {{0.f,0.f,0.f,0.f}, {0.f,0.f,0.f,0.f}};
        #pragma unroll
        for (int hh = 0; hh < 4; ++hh)
            #pragma unroll
            for (int jb = 0; jb < 2; ++jb)
                #pragma unroll
                for (int r = 0; r < 4; ++r) {
                    float e = (mvv[jb][r] == 0) ? 1.0f : __expf(0.125f * sc[hh][jb][r]);
                    sc[hh][jb][r] = e;
                    ps[jb][r] += e;
                }

        // ---- cross-wave sum; layout word=(jcol*4+w)*17+n16 (2-way banks)
        float* rb = red + (t & 1) * 2176;
        #pragma unroll
        for (int jb = 0; jb < 2; ++jb)
            #pragma unroll
            for (int r = 0; r < 4; ++r)
                rb[((jb * 16 + g4 + r) * 4 + w) * 17 + n16] = ps[jb][r];
        asm volatile("s_waitcnt lgkmcnt(0)" ::: "memory");
        __builtin_amdgcn_s_barrier();   // lgkm-only: global loads stay in flight

        float inv_[2][4];
        #pragma unroll
        for (int jb = 0; jb < 2; ++jb)
            #pragma unroll
            for (int r = 0; r < 4; ++r) {
                const int jc = (jb * 16 + g4 + r) * 4;
                float s = rb[(jc + 0) * 17 + n16] + rb[(jc + 1) * 17 + n16]
                        + rb[(jc + 2) * 17 + n16] + rb[(jc + 3) * 17 + n16];
                inv_[jb][r] = 1.0f / s;
            }

        // ---- P: stash f16 in per-wave LDS + PV accumulate from regs
        #pragma unroll
        for (int hh = 0; hh < 4; ++hh) {
            half_t* pb_head = pbuf + (size_t)(w * 4 + hh) * 16 * 36;
            const half_t* vp = vt + (hb0 + h0 + hh) * (size_t)HSZ;
            #pragma unroll
            for (int jb = 0; jb < 2; ++jb) {
                f16x4 pb;
                #pragma unroll
                for (int r = 0; r < 4; ++r) pb[r] = (half_t)(sc[hh][jb][r] * inv_[jb][r]);
                *(f16x4*)(pb_head + n16 * 36 + jb * 16 + g4) = pb;  // 8B-aligned (stride 72B)
                #pragma unroll
                for (int ds = 0; ds < 4; ++ds) {
                    f16x4 av = *(const f16x4*)(vp + (size_t)(ds * 16 + n16) * LSEQ + j0 + jb * 16 + g4);
                    acc[hh][ds] = __builtin_amdgcn_mfma_f32_16x16x16f16(av, pb, acc[hh][ds], 0, 0, 0);
                }
            }
        }

        // ---- score store: full-128B-line nontemporal (wave-private pbuf)
        const int srow_ = lane >> 3, scol = (lane & 7) * 4;
        #pragma unroll
        for (int hh = 0; hh < 4; ++hh) {
            const half_t* pb_head = pbuf + (size_t)(w * 4 + hh) * 16 * 36;
            float* sbase = score + ((hb0 + h0 + hh) * LSEQ + i0) * LSEQ + j0;
            #pragma unroll
            for (int half_i = 0; half_i < 2; ++half_i) {
                const int row = half_i * 8 + srow_;
                f16x4 x = *(const f16x4*)(pb_head + row * 36 + scol);
                f32x4 y;
                y[0] = (float)x[0]; y[1] = (float)x[1]; y[2] = (float)x[2]; y[3] = (float)x[3];
                __builtin_nontemporal_store(y, (f32x4*)(sbase + (size_t)row * LSEQ + scol));
            }
        }
    }

    // ---- epilogue: wave-local LDS transpose of partial out^T -> full-line nt
    __syncthreads();                      // red region reused below
    float* pbase = pout + (size_t)jslice * NELEM;
    float* ep = (float*)smem_raw + w * 1088;   // 16 rows x stride 68 f32
    const int erow = lane >> 4, ecol = (lane & 15) * 4;
    #pragma unroll
    for (int hh = 0; hh < 4; ++hh) {
        #pragma unroll
        for (int ds = 0; ds < 4; ++ds)
            *(f32x4*)&ep[n16 * 68 + ds * 16 + g4] = acc[hh][ds];
        asm volatile("s_waitcnt lgkmcnt(0)" ::: "memory");
        float* obase = pbase + (hb0 + h0 + hh) * (size_t)HSZ + (size_t)i0 * DD;
        #pragma unroll
        for (int qq = 0; qq < 4; ++qq) {
            const int row = qq * 4 + erow;
            f32x4 x = *(const f32x4*)&ep[row * 68 + ecol];
            __builtin_nontemporal_store(x, (f32x4*)(obase + (size_t)row * DD + ecol));
        }
        asm volatile("s_waitcnt lgkmcnt(0)" ::: "memory");
    }
}

// ---------------- Reduce: out = sum of 4 partial slices ----------------
__global__ __launch_bounds__(256) void reduce_out(
    const float* __restrict__ pout, float* __restrict__ out)
{
    const int n4 = NELEM / 4;
    for (int i = blockIdx.x * 256 + threadIdx.x; i < n4; i += gridDim.x * 256) {
        f32x4 a = __builtin_nontemporal_load((const f32x4*)pout + i);
        f32x4 bb = __builtin_nontemporal_load((const f32x4*)(pout + NELEM) + i);
        f32x4 c = __builtin_nontemporal_load((const f32x4*)(pout + 2 * (size_t)NELEM) + i);
        f32x4 d = __builtin_nontemporal_load((const f32x4*)(pout + 3 * (size_t)NELEM) + i);
        __builtin_nontemporal_store(a + bb + c + d, (f32x4*)out + i);
    }
}

extern "C" void kernel_launch(void* const* d_in, const int* in_sizes, int n_in,
                              void* d_out, int out_size, void* d_ws, size_t ws_size,
                              hipStream_t stream) {
    const float* q    = (const float*)d_in[0];
    const float* k    = (const float*)d_in[1];
    const float* v    = (const float*)d_in[2];
    const int*   mask = (const int*)d_in[3];

    float* out   = (float*)d_out;
    float* score = out + (size_t)NB * NH * LSEQ * DD;

    half_t* qh   = (half_t*)d_ws;            // 8 MB
    half_t* kt   = qh + NELEM;               // 8 MB  kt[b,h][j][d]
    half_t* vt   = kt + NELEM;               // 8 MB  vt[b,h][d][j]
    float*  pout = (float*)(vt + NELEM);     // 4 x 16 MB partial outputs

    convert_q<<<2048, 256, 0, stream>>>(q, qh);
    transpose_cvt<<<dim3(32, NB * NH, 2), 256, 0, stream>>>(k, v, kt, vt);
    fused_attn_part<<<1024, 256, 0, stream>>>(qh, kt, vt, mask, score, pout);
    reduce_out<<<1024, 256, 0, stream>>>(pout, out);
}